// Round 1
// baseline (588.003 us; speedup 1.0000x reference)
//
#include <hip/hip_runtime.h>
#include <hip/hip_bf16.h>
#include <math.h>

// Problem dims (fixed by reference setup_inputs)
#define D_IN   1024
#define D_HID  4096
#define M_TOK  16384   // 4 * 4096 tokens

typedef int v4i __attribute__((ext_vector_type(4)));
typedef _Float16 f16x8 __attribute__((ext_vector_type(8)));

// ---------------- workspace layout (bytes) ----------------
#define OFF_SLOTS  ((size_t)0)                                   // 8 x u32 atomic slots
#define OFF_SCAL   ((size_t)64)                                  // 16 x f32 scalars
#define OFF_ISCAL  ((size_t)128)                                 // 8 x i32
#define OFF_XQ     ((size_t)256)                                 // 16M  int8
#define OFF_W1Q    (OFF_XQ  + (size_t)M_TOK * D_IN)              // 4M   int8
#define OFF_W2Q    (OFF_W1Q + (size_t)D_HID * D_IN)              // 4M   int8
#define OFF_RS1    (OFF_W2Q + (size_t)D_IN * D_HID)              // 16K  i32
#define OFF_RS2    (OFF_RS1 + (size_t)D_HID * 4)                 // 4K   i32
#define OFF_H      (OFF_RS2 + (size_t)D_IN * 4 + 128)            // 128M fp16
#define OFF_HQ     (OFF_H   + (size_t)M_TOK * D_HID * 2)         // 64M  int8
// total ~226.5 MB

// slots: [0] x min(enc) [1] x max(enc) [2] |W1|max bits [3] |W2|max bits
//        [4] h min(enc) [5] h max(enc)
// scal:  [0] sx1 [1] zx1f [2] sw1 [3] sw2 [4] s1=sx1*sw1 [5] sx2 [6] zx2f [7] s2=sx2*sw2
// iscal: [0] zx1 [1] zx2

__device__ inline unsigned enc_f(float f) {
    unsigned u = __float_as_uint(f);
    return (u & 0x80000000u) ? ~u : (u | 0x80000000u);
}
__device__ inline float dec_f(unsigned u) {
    return __uint_as_float((u & 0x80000000u) ? (u ^ 0x80000000u) : ~u);
}

__global__ void k_init(unsigned* slots) {
    int t = threadIdx.x;
    if (t < 8) slots[t] = (t == 0 || t == 4) ? 0xFFFFFFFFu : 0u;
}

__global__ void k_minmax(const float4* __restrict__ x, int n4, unsigned* slots) {
    float vmin = 3.4e38f, vmax = -3.4e38f;
    for (int i = blockIdx.x * blockDim.x + threadIdx.x; i < n4; i += gridDim.x * blockDim.x) {
        float4 v = x[i];
        vmin = fminf(vmin, fminf(fminf(v.x, v.y), fminf(v.z, v.w)));
        vmax = fmaxf(vmax, fmaxf(fmaxf(v.x, v.y), fmaxf(v.z, v.w)));
    }
    for (int off = 32; off > 0; off >>= 1) {
        vmin = fminf(vmin, __shfl_down(vmin, off));
        vmax = fmaxf(vmax, __shfl_down(vmax, off));
    }
    __shared__ float red[8];
    int wave = threadIdx.x >> 6, lane = threadIdx.x & 63;
    if (lane == 0) { red[wave] = vmin; red[4 + wave] = vmax; }
    __syncthreads();
    if (threadIdx.x == 0) {
        float bmin = fminf(fminf(red[0], red[1]), fminf(red[2], red[3]));
        float bmax = fmaxf(fmaxf(red[4], red[5]), fmaxf(red[6], red[7]));
        atomicMin(&slots[0], enc_f(bmin));
        atomicMax(&slots[1], enc_f(bmax));
    }
}

__global__ void k_absmax(const float4* __restrict__ w, int n4, unsigned* slots, int slot) {
    float vmax = 0.0f;
    for (int i = blockIdx.x * blockDim.x + threadIdx.x; i < n4; i += gridDim.x * blockDim.x) {
        float4 v = w[i];
        vmax = fmaxf(vmax, fmaxf(fmaxf(fabsf(v.x), fabsf(v.y)), fmaxf(fabsf(v.z), fabsf(v.w))));
    }
    for (int off = 32; off > 0; off >>= 1)
        vmax = fmaxf(vmax, __shfl_down(vmax, off));
    __shared__ float red[4];
    int wave = threadIdx.x >> 6, lane = threadIdx.x & 63;
    if (lane == 0) red[wave] = vmax;
    __syncthreads();
    if (threadIdx.x == 0) {
        float bmax = fmaxf(fmaxf(red[0], red[1]), fmaxf(red[2], red[3]));
        atomicMax(&slots[slot], __float_as_uint(bmax));  // bmax >= 0: raw bits monotone
    }
}

__global__ void k_scales1(const unsigned* slots, float* scal, int* iscal) {
    float amin = dec_f(slots[0]), amax = dec_f(slots[1]);
    float sx = fmaxf((amax - amin) / 255.0f, 1e-8f);
    float zx = rintf(-amin / sx) - 128.0f;
    zx = fminf(fmaxf(zx, -128.0f), 127.0f);
    float sw1 = fmaxf(__uint_as_float(slots[2]) / 127.0f, 1e-8f);
    float sw2 = fmaxf(__uint_as_float(slots[3]) / 127.0f, 1e-8f);
    scal[0] = sx; scal[1] = zx; scal[2] = sw1; scal[3] = sw2; scal[4] = sx * sw1;
    iscal[0] = (int)zx;
}

__global__ void k_scales2(const unsigned* slots, float* scal, int* iscal) {
    float amin = dec_f(slots[4]), amax = dec_f(slots[5]);
    float s = fmaxf((amax - amin) / 255.0f, 1e-8f);
    float zp = rintf(-amin / s) - 128.0f;
    zp = fminf(fmaxf(zp, -128.0f), 127.0f);
    scal[5] = s; scal[6] = zp; scal[7] = s * scal[3];
    iscal[1] = (int)zp;
}

__global__ void k_quant_x(const float4* __restrict__ x, int* __restrict__ xq, int n4,
                          const float* __restrict__ scal) {
    float s = scal[0], zp = scal[1];
    for (int i = blockIdx.x * blockDim.x + threadIdx.x; i < n4; i += gridDim.x * blockDim.x) {
        float4 v = x[i];
        int a = (int)fminf(fmaxf(rintf(v.x / s) + zp, -128.0f), 127.0f);
        int b = (int)fminf(fmaxf(rintf(v.y / s) + zp, -128.0f), 127.0f);
        int c = (int)fminf(fmaxf(rintf(v.z / s) + zp, -128.0f), 127.0f);
        int d = (int)fminf(fmaxf(rintf(v.w / s) + zp, -128.0f), 127.0f);
        xq[i] = (a & 255) | ((b & 255) << 8) | ((c & 255) << 16) | ((d & 255) << 24);
    }
}

// one block per weight row: quantize + row sum
__global__ void k_quant_w(const float* __restrict__ W, signed char* __restrict__ Wq,
                          int* __restrict__ rsum, int K, const float* __restrict__ scal, int sslot) {
    float s = scal[sslot];
    int row = blockIdx.x;
    const float4* Wr = (const float4*)(W + (size_t)row * K);
    int* out = (int*)(Wq + (size_t)row * K);
    int mysum = 0;
    for (int i = threadIdx.x; i < K / 4; i += blockDim.x) {
        float4 v = Wr[i];
        int a = (int)fminf(fmaxf(rintf(v.x / s), -127.0f), 127.0f);
        int b = (int)fminf(fmaxf(rintf(v.y / s), -127.0f), 127.0f);
        int c = (int)fminf(fmaxf(rintf(v.z / s), -127.0f), 127.0f);
        int d = (int)fminf(fmaxf(rintf(v.w / s), -127.0f), 127.0f);
        mysum += a + b + c + d;
        out[i] = (a & 255) | ((b & 255) << 8) | ((c & 255) << 16) | ((d & 255) << 24);
    }
    for (int off = 32; off > 0; off >>= 1)
        mysum += __shfl_down(mysum, off);
    __shared__ int red[4];
    int wave = threadIdx.x >> 6, lane = threadIdx.x & 63;
    if (lane == 0) red[wave] = mysum;
    __syncthreads();
    if (threadIdx.x == 0) rsum[row] = red[0] + red[1] + red[2] + red[3];
}

__global__ void k_quant_h(const f16x8* __restrict__ H, int2* __restrict__ Hq, int n8,
                          const float* __restrict__ scal) {
    float s = scal[5], zp = scal[6];
    for (int i = blockIdx.x * blockDim.x + threadIdx.x; i < n8; i += gridDim.x * blockDim.x) {
        f16x8 v = H[i];
        int q[8];
#pragma unroll
        for (int j = 0; j < 8; j++)
            q[j] = ((int)fminf(fmaxf(rintf((float)v[j] / s) + zp, -128.0f), 127.0f)) & 255;
        int lo = q[0] | (q[1] << 8) | (q[2] << 16) | (q[3] << 24);
        int hi = q[4] | (q[5] << 8) | (q[6] << 16) | (q[7] << 24);
        Hq[i] = make_int2(lo, hi);
    }
}

// ---------------- int8 MFMA GEMM mainloop ----------------
// C[m][n] = sum_k A[m][k] * B[n][k]   (both row-major, K contiguous)
// 128x128 tile, BK=64, 256 threads (4 waves, 2x2 wave grid, 4x4 16x16 tiles/wave)
__device__ inline void int8_mainloop(const signed char* __restrict__ A,
                                     const signed char* __restrict__ B,
                                     int K, int m0, int n0,
                                     signed char* As, signed char* Bs, v4i acc[4][4]) {
    const int tid = threadIdx.x;
    const int lane = tid & 63, wave = tid >> 6;
    const int wm = (wave & 1) << 6, wn = (wave >> 1) << 6;
    const int lm = lane & 15, lq = lane >> 4;
    const int r = tid >> 2, c = (tid & 3) << 4;
    const long arow0 = (long)(m0 + r) * K,      arow1 = (long)(m0 + r + 64) * K;
    const long brow0 = (long)(n0 + r) * K,      brow1 = (long)(n0 + r + 64) * K;
    for (int k0 = 0; k0 < K; k0 += 64) {
        __syncthreads();
        *(int4*)&As[r * 64 + c]        = *(const int4*)&A[arow0 + k0 + c];
        *(int4*)&As[(r + 64) * 64 + c] = *(const int4*)&A[arow1 + k0 + c];
        *(int4*)&Bs[r * 64 + c]        = *(const int4*)&B[brow0 + k0 + c];
        *(int4*)&Bs[(r + 64) * 64 + c] = *(const int4*)&B[brow1 + k0 + c];
        __syncthreads();
        v4i av[4], bv[4];
#pragma unroll
        for (int i = 0; i < 4; i++)
            av[i] = *(const v4i*)&As[(wm + i * 16 + lm) * 64 + lq * 16];
#pragma unroll
        for (int j = 0; j < 4; j++)
            bv[j] = *(const v4i*)&Bs[(wn + j * 16 + lm) * 64 + lq * 16];
#pragma unroll
        for (int i = 0; i < 4; i++)
#pragma unroll
            for (int j = 0; j < 4; j++)
                acc[i][j] = __builtin_amdgcn_mfma_i32_16x16x64_i8(av[i], bv[j], acc[i][j], 0, 0, 0);
    }
}

__global__ __launch_bounds__(256) void k_gemm1(const signed char* __restrict__ Aq,
                                               const signed char* __restrict__ Bq,
                                               _Float16* __restrict__ H,
                                               const float* __restrict__ scal,
                                               const int* __restrict__ iscal,
                                               const int* __restrict__ rsum,
                                               const float* __restrict__ bias,
                                               unsigned* slots) {
    __shared__ __align__(16) signed char As[128 * 64];
    __shared__ __align__(16) signed char Bs[128 * 64];
    const int nb = D_HID / 128;
    const int m0 = (blockIdx.x / nb) * 128, n0 = (blockIdx.x % nb) * 128;
    v4i acc[4][4];
    v4i zero = {0, 0, 0, 0};
#pragma unroll
    for (int i = 0; i < 4; i++)
#pragma unroll
        for (int j = 0; j < 4; j++) acc[i][j] = zero;
    int8_mainloop(Aq, Bq, D_IN, m0, n0, As, Bs, acc);

    const int tid = threadIdx.x, lane = tid & 63, wave = tid >> 6;
    const int wm = (wave & 1) << 6, wn = (wave >> 1) << 6;
    const int lm = lane & 15, lq = lane >> 4;
    float s1 = scal[4];
    int zx = iscal[0];
    float lmin = 3.4e38f, lmax = -3.4e38f;
#pragma unroll
    for (int j = 0; j < 4; j++) {
        int n = n0 + wn + j * 16 + lm;
        int rsn = rsum[n];
        float bn = bias[n];
#pragma unroll
        for (int i = 0; i < 4; i++) {
            int mb = m0 + wm + i * 16 + lq * 4;
#pragma unroll
            for (int rg = 0; rg < 4; rg++) {
                int v = acc[i][j][rg] - zx * rsn;
                float f = (float)v * s1 + bn;
                float g = f * 0.5f * (1.0f + erff(f * 0.7071067811865476f));
                _Float16 gh = (_Float16)g;
                H[(long)(mb + rg) * D_HID + n] = gh;
                float gf = (float)gh;
                lmin = fminf(lmin, gf);
                lmax = fmaxf(lmax, gf);
            }
        }
    }
    for (int off = 32; off > 0; off >>= 1) {
        lmin = fminf(lmin, __shfl_down(lmin, off));
        lmax = fmaxf(lmax, __shfl_down(lmax, off));
    }
    __syncthreads();
    float* red = (float*)As;
    if (lane == 0) { red[wave] = lmin; red[4 + wave] = lmax; }
    __syncthreads();
    if (tid == 0) {
        atomicMin(&slots[4], enc_f(fminf(fminf(red[0], red[1]), fminf(red[2], red[3]))));
        atomicMax(&slots[5], enc_f(fmaxf(fmaxf(red[4], red[5]), fmaxf(red[6], red[7]))));
    }
}

__global__ __launch_bounds__(256) void k_gemm2(const signed char* __restrict__ Aq,
                                               const signed char* __restrict__ Bq,
                                               float* __restrict__ Out,
                                               const float* __restrict__ scal,
                                               const int* __restrict__ iscal,
                                               const int* __restrict__ rsum,
                                               const float* __restrict__ bias) {
    __shared__ __align__(16) signed char As[128 * 64];
    __shared__ __align__(16) signed char Bs[128 * 64];
    const int nb = D_IN / 128;
    const int m0 = (blockIdx.x / nb) * 128, n0 = (blockIdx.x % nb) * 128;
    v4i acc[4][4];
    v4i zero = {0, 0, 0, 0};
#pragma unroll
    for (int i = 0; i < 4; i++)
#pragma unroll
        for (int j = 0; j < 4; j++) acc[i][j] = zero;
    int8_mainloop(Aq, Bq, D_HID, m0, n0, As, Bs, acc);

    const int tid = threadIdx.x, lane = tid & 63, wave = tid >> 6;
    const int wm = (wave & 1) << 6, wn = (wave >> 1) << 6;
    const int lm = lane & 15, lq = lane >> 4;
    float s2 = scal[7];
    int zx = iscal[1];
#pragma unroll
    for (int j = 0; j < 4; j++) {
        int n = n0 + wn + j * 16 + lm;
        int rsn = rsum[n];
        float bn = bias[n];
#pragma unroll
        for (int i = 0; i < 4; i++) {
            int mb = m0 + wm + i * 16 + lq * 4;
#pragma unroll
            for (int rg = 0; rg < 4; rg++) {
                int v = acc[i][j][rg] - zx * rsn;
                Out[(long)(mb + rg) * D_IN + n] = (float)v * s2 + bn;
            }
        }
    }
}

extern "C" void kernel_launch(void* const* d_in, const int* in_sizes, int n_in,
                              void* d_out, int out_size, void* d_ws, size_t ws_size,
                              hipStream_t stream) {
    const float* x  = (const float*)d_in[0];
    const float* W1 = (const float*)d_in[1];
    const float* b1 = (const float*)d_in[2];
    const float* W2 = (const float*)d_in[3];
    const float* b2 = (const float*)d_in[4];

    char* ws = (char*)d_ws;
    unsigned* slots    = (unsigned*)(ws + OFF_SLOTS);
    float* scal        = (float*)(ws + OFF_SCAL);
    int* iscal         = (int*)(ws + OFF_ISCAL);
    signed char* xq    = (signed char*)(ws + OFF_XQ);
    signed char* w1q   = (signed char*)(ws + OFF_W1Q);
    signed char* w2q   = (signed char*)(ws + OFF_W2Q);
    int* rs1           = (int*)(ws + OFF_RS1);
    int* rs2           = (int*)(ws + OFF_RS2);
    _Float16* h        = (_Float16*)(ws + OFF_H);
    signed char* hq    = (signed char*)(ws + OFF_HQ);

    k_init<<<1, 64, 0, stream>>>(slots);
    k_minmax<<<2048, 256, 0, stream>>>((const float4*)x, M_TOK * D_IN / 4, slots);
    k_absmax<<<512, 256, 0, stream>>>((const float4*)W1, D_HID * D_IN / 4, slots, 2);
    k_absmax<<<512, 256, 0, stream>>>((const float4*)W2, D_IN * D_HID / 4, slots, 3);
    k_scales1<<<1, 1, 0, stream>>>(slots, scal, iscal);
    k_quant_x<<<2048, 256, 0, stream>>>((const float4*)x, (int*)xq, M_TOK * D_IN / 4, scal);
    k_quant_w<<<D_HID, 256, 0, stream>>>(W1, w1q, rs1, D_IN, scal, 2);
    k_quant_w<<<D_IN, 256, 0, stream>>>(W2, w2q, rs2, D_HID, scal, 3);
    k_gemm1<<<(M_TOK / 128) * (D_HID / 128), 256, 0, stream>>>(xq, w1q, h, scal, iscal, rs1, b1, slots);
    k_scales2<<<1, 1, 0, stream>>>(slots, scal, iscal);
    k_quant_h<<<4096, 256, 0, stream>>>((const f16x8*)h, (int2*)hq, M_TOK * D_HID / 8, scal);
    k_gemm2<<<(M_TOK / 128) * (D_IN / 128), 256, 0, stream>>>(hq, w2q, (float*)d_out, scal, iscal, rs2, b2);
}

// Round 2
// 570.720 us; speedup vs baseline: 1.0303x; 1.0303x over previous
//
#include <hip/hip_runtime.h>
#include <hip/hip_bf16.h>
#include <math.h>

// Problem dims (fixed by reference setup_inputs)
#define D_IN   1024
#define D_HID  4096
#define M_TOK  16384   // 4 * 4096 tokens

typedef int v4i __attribute__((ext_vector_type(4)));
typedef _Float16 f16x8 __attribute__((ext_vector_type(8)));

typedef __attribute__((address_space(3))) unsigned int lds_u32;
typedef const __attribute__((address_space(1))) unsigned int glb_u32;

// async global->LDS, 16B per lane, wave-uniform LDS base + lane*16
__device__ inline void gload_lds16(const signed char* g, signed char* l) {
    __builtin_amdgcn_global_load_lds((glb_u32*)g, (lds_u32*)l, 16, 0, 0);
}

// ---------------- workspace layout (bytes) ----------------
#define OFF_SLOTS  ((size_t)0)                                   // 8 x u32 atomic slots
#define OFF_SCAL   ((size_t)64)                                  // 16 x f32 scalars
#define OFF_ISCAL  ((size_t)128)                                 // 8 x i32
#define OFF_XQ     ((size_t)256)                                 // 16M  int8
#define OFF_W1Q    (OFF_XQ  + (size_t)M_TOK * D_IN)              // 4M   int8
#define OFF_W2Q    (OFF_W1Q + (size_t)D_HID * D_IN)              // 4M   int8
#define OFF_RS1    (OFF_W2Q + (size_t)D_IN * D_HID)              // 16K  i32
#define OFF_RS2    (OFF_RS1 + (size_t)D_HID * 4)                 // 4K   i32
#define OFF_H      (OFF_RS2 + (size_t)D_IN * 4 + 128)            // 128M fp16
#define OFF_HQ     (OFF_H   + (size_t)M_TOK * D_HID * 2)         // 64M  int8
// total ~226.5 MB

// slots: [0] x min(enc) [1] x max(enc) [2] |W1|max bits [3] |W2|max bits
//        [4] h min(enc) [5] h max(enc)
// scal:  [0] sx1 [1] zx1f [2] sw1 [3] sw2 [4] s1=sx1*sw1 [5] sx2 [6] zx2f [7] s2=sx2*sw2
// iscal: [0] zx1 [1] zx2

__device__ inline unsigned enc_f(float f) {
    unsigned u = __float_as_uint(f);
    return (u & 0x80000000u) ? ~u : (u | 0x80000000u);
}
__device__ inline float dec_f(unsigned u) {
    return __uint_as_float((u & 0x80000000u) ? (u ^ 0x80000000u) : ~u);
}

__global__ void k_init(unsigned* slots) {
    int t = threadIdx.x;
    if (t < 8) slots[t] = (t == 0 || t == 4) ? 0xFFFFFFFFu : 0u;
}

__global__ void k_minmax(const float4* __restrict__ x, int n4, unsigned* slots) {
    float vmin = 3.4e38f, vmax = -3.4e38f;
    for (int i = blockIdx.x * blockDim.x + threadIdx.x; i < n4; i += gridDim.x * blockDim.x) {
        float4 v = x[i];
        vmin = fminf(vmin, fminf(fminf(v.x, v.y), fminf(v.z, v.w)));
        vmax = fmaxf(vmax, fmaxf(fmaxf(v.x, v.y), fmaxf(v.z, v.w)));
    }
    for (int off = 32; off > 0; off >>= 1) {
        vmin = fminf(vmin, __shfl_down(vmin, off));
        vmax = fmaxf(vmax, __shfl_down(vmax, off));
    }
    __shared__ float red[8];
    int wave = threadIdx.x >> 6, lane = threadIdx.x & 63;
    if (lane == 0) { red[wave] = vmin; red[4 + wave] = vmax; }
    __syncthreads();
    if (threadIdx.x == 0) {
        float bmin = fminf(fminf(red[0], red[1]), fminf(red[2], red[3]));
        float bmax = fmaxf(fmaxf(red[4], red[5]), fmaxf(red[6], red[7]));
        atomicMin(&slots[0], enc_f(bmin));
        atomicMax(&slots[1], enc_f(bmax));
    }
}

__global__ void k_absmax(const float4* __restrict__ w, int n4, unsigned* slots, int slot) {
    float vmax = 0.0f;
    for (int i = blockIdx.x * blockDim.x + threadIdx.x; i < n4; i += gridDim.x * blockDim.x) {
        float4 v = w[i];
        vmax = fmaxf(vmax, fmaxf(fmaxf(fabsf(v.x), fabsf(v.y)), fmaxf(fabsf(v.z), fabsf(v.w))));
    }
    for (int off = 32; off > 0; off >>= 1)
        vmax = fmaxf(vmax, __shfl_down(vmax, off));
    __shared__ float red[4];
    int wave = threadIdx.x >> 6, lane = threadIdx.x & 63;
    if (lane == 0) red[wave] = vmax;
    __syncthreads();
    if (threadIdx.x == 0) {
        float bmax = fmaxf(fmaxf(red[0], red[1]), fmaxf(red[2], red[3]));
        atomicMax(&slots[slot], __float_as_uint(bmax));  // bmax >= 0: raw bits monotone
    }
}

__global__ void k_scales1(const unsigned* slots, float* scal, int* iscal) {
    float amin = dec_f(slots[0]), amax = dec_f(slots[1]);
    float sx = fmaxf((amax - amin) / 255.0f, 1e-8f);
    float zx = rintf(-amin / sx) - 128.0f;
    zx = fminf(fmaxf(zx, -128.0f), 127.0f);
    float sw1 = fmaxf(__uint_as_float(slots[2]) / 127.0f, 1e-8f);
    float sw2 = fmaxf(__uint_as_float(slots[3]) / 127.0f, 1e-8f);
    scal[0] = sx; scal[1] = zx; scal[2] = sw1; scal[3] = sw2; scal[4] = sx * sw1;
    iscal[0] = (int)zx;
}

__global__ void k_scales2(const unsigned* slots, float* scal, int* iscal) {
    float amin = dec_f(slots[4]), amax = dec_f(slots[5]);
    float s = fmaxf((amax - amin) / 255.0f, 1e-8f);
    float zp = rintf(-amin / s) - 128.0f;
    zp = fminf(fmaxf(zp, -128.0f), 127.0f);
    scal[5] = s; scal[6] = zp; scal[7] = s * scal[3];
    iscal[1] = (int)zp;
}

__global__ void k_quant_x(const float4* __restrict__ x, int* __restrict__ xq, int n4,
                          const float* __restrict__ scal) {
    float s = scal[0], zp = scal[1];
    for (int i = blockIdx.x * blockDim.x + threadIdx.x; i < n4; i += gridDim.x * blockDim.x) {
        float4 v = x[i];
        int a = (int)fminf(fmaxf(rintf(v.x / s) + zp, -128.0f), 127.0f);
        int b = (int)fminf(fmaxf(rintf(v.y / s) + zp, -128.0f), 127.0f);
        int c = (int)fminf(fmaxf(rintf(v.z / s) + zp, -128.0f), 127.0f);
        int d = (int)fminf(fmaxf(rintf(v.w / s) + zp, -128.0f), 127.0f);
        xq[i] = (a & 255) | ((b & 255) << 8) | ((c & 255) << 16) | ((d & 255) << 24);
    }
}

// one block per weight row: quantize + row sum
__global__ void k_quant_w(const float* __restrict__ W, signed char* __restrict__ Wq,
                          int* __restrict__ rsum, int K, const float* __restrict__ scal, int sslot) {
    float s = scal[sslot];
    int row = blockIdx.x;
    const float4* Wr = (const float4*)(W + (size_t)row * K);
    int* out = (int*)(Wq + (size_t)row * K);
    int mysum = 0;
    for (int i = threadIdx.x; i < K / 4; i += blockDim.x) {
        float4 v = Wr[i];
        int a = (int)fminf(fmaxf(rintf(v.x / s), -127.0f), 127.0f);
        int b = (int)fminf(fmaxf(rintf(v.y / s), -127.0f), 127.0f);
        int c = (int)fminf(fmaxf(rintf(v.z / s), -127.0f), 127.0f);
        int d = (int)fminf(fmaxf(rintf(v.w / s), -127.0f), 127.0f);
        mysum += a + b + c + d;
        out[i] = (a & 255) | ((b & 255) << 8) | ((c & 255) << 16) | ((d & 255) << 24);
    }
    for (int off = 32; off > 0; off >>= 1)
        mysum += __shfl_down(mysum, off);
    __shared__ int red[4];
    int wave = threadIdx.x >> 6, lane = threadIdx.x & 63;
    if (lane == 0) red[wave] = mysum;
    __syncthreads();
    if (threadIdx.x == 0) rsum[row] = red[0] + red[1] + red[2] + red[3];
}

__global__ void k_quant_h(const f16x8* __restrict__ H, int2* __restrict__ Hq, int n8,
                          const float* __restrict__ scal) {
    float s = scal[5], zp = scal[6];
    for (int i = blockIdx.x * blockDim.x + threadIdx.x; i < n8; i += gridDim.x * blockDim.x) {
        f16x8 v = H[i];
        int q[8];
#pragma unroll
        for (int j = 0; j < 8; j++)
            q[j] = ((int)fminf(fmaxf(rintf((float)v[j] / s) + zp, -128.0f), 127.0f)) & 255;
        int lo = q[0] | (q[1] << 8) | (q[2] << 16) | (q[3] << 24);
        int hi = q[4] | (q[5] << 8) | (q[6] << 16) | (q[7] << 24);
        Hq[i] = make_int2(lo, hi);
    }
}

// ---------------- int8 MFMA GEMM mainloop ----------------
// C[m][n] = sum_k A[m][k] * B[n][k]   (both row-major, K contiguous)
// 128x128 tile, BK=64, 256 threads (4 waves, 2x2 wave grid, 4x4 16x16 tiles/wave)
// Staging: global_load_lds width=16 (async DMA, no VGPR roundtrip).
// LDS swizzle: chunk (row, c) holds global chunk (row, c ^ ((row>>1)&3));
// reader f = lq ^ ((lm>>1)&3) -> bank-group (lm*4+f) mod 8 hit exactly 2x over
// 16 rows = 2-way aliasing = free (m136). Swizzle lives in the SOURCE address,
// preserving the DMA's contiguous base+lane*16 LDS layout (m104/m108 caveat).
__device__ inline void int8_mainloop(const signed char* __restrict__ A,
                                     const signed char* __restrict__ B,
                                     int K, int m0, int n0,
                                     signed char* As, signed char* Bs, v4i acc[4][4]) {
    const int tid = threadIdx.x;
    const int lane = tid & 63, wave = tid >> 6;
    const int wm = (wave & 1) << 6, wn = (wave >> 1) << 6;
    const int lm = lane & 15, lq = lane >> 4;

    // staging assignment: wave w stages rows [w*32, w*32+32) of A and B tiles,
    // two DMA instructions each (16 rows x 4 chunks = 64 lanes x 16B = 1KB)
    const int r0 = wave * 32 + (lane >> 2);      // t=0 rows
    const int r1 = r0 + 16;                      // t=1 rows
    const int c  = lane & 3;
    const int col0 = c ^ ((r0 >> 1) & 3);
    const int col1 = c ^ ((r1 >> 1) & 3);

    const signed char* gA0 = A + (long)(m0 + r0) * K + col0 * 16;
    const signed char* gA1 = A + (long)(m0 + r1) * K + col1 * 16;
    const signed char* gB0 = B + (long)(n0 + r0) * K + col0 * 16;
    const signed char* gB1 = B + (long)(n0 + r1) * K + col1 * 16;
    signed char* lA0 = As + (wave * 32) * 64 + lane * 16;
    signed char* lA1 = As + (wave * 32 + 16) * 64 + lane * 16;
    signed char* lB0 = Bs + (wave * 32) * 64 + lane * 16;
    signed char* lB1 = Bs + (wave * 32 + 16) * 64 + lane * 16;

    // fragment-read swizzle, independent of tile index i
    const int f = lq ^ ((lm >> 1) & 3);

    for (int k0 = 0; k0 < K; k0 += 64) {
        __syncthreads();
        gload_lds16(gA0, lA0);
        gload_lds16(gA1, lA1);
        gload_lds16(gB0, lB0);
        gload_lds16(gB1, lB1);
        gA0 += 64; gA1 += 64; gB0 += 64; gB1 += 64;
        asm volatile("s_waitcnt vmcnt(0)" ::: "memory");
        __syncthreads();
        v4i av[4], bv[4];
#pragma unroll
        for (int i = 0; i < 4; i++)
            av[i] = *(const v4i*)&As[(wm + i * 16 + lm) * 64 + f * 16];
#pragma unroll
        for (int j = 0; j < 4; j++)
            bv[j] = *(const v4i*)&Bs[(wn + j * 16 + lm) * 64 + f * 16];
#pragma unroll
        for (int i = 0; i < 4; i++)
#pragma unroll
            for (int j = 0; j < 4; j++)
                acc[i][j] = __builtin_amdgcn_mfma_i32_16x16x64_i8(av[i], bv[j], acc[i][j], 0, 0, 0);
    }
}

__global__ __launch_bounds__(256) void k_gemm1(const signed char* __restrict__ Aq,
                                               const signed char* __restrict__ Bq,
                                               _Float16* __restrict__ H,
                                               const float* __restrict__ scal,
                                               const int* __restrict__ iscal,
                                               const int* __restrict__ rsum,
                                               const float* __restrict__ bias,
                                               unsigned* slots) {
    __shared__ __align__(16) signed char As[128 * 64];
    __shared__ __align__(16) signed char Bs[128 * 64];
    const int nb = D_HID / 128;
    const int m0 = (blockIdx.x / nb) * 128, n0 = (blockIdx.x % nb) * 128;
    v4i acc[4][4];
    v4i zero = {0, 0, 0, 0};
#pragma unroll
    for (int i = 0; i < 4; i++)
#pragma unroll
        for (int j = 0; j < 4; j++) acc[i][j] = zero;
    int8_mainloop(Aq, Bq, D_IN, m0, n0, As, Bs, acc);

    const int tid = threadIdx.x, lane = tid & 63, wave = tid >> 6;
    const int wm = (wave & 1) << 6, wn = (wave >> 1) << 6;
    const int lm = lane & 15, lq = lane >> 4;
    float s1 = scal[4];
    int zx = iscal[0];
    float lmin = 3.4e38f, lmax = -3.4e38f;
#pragma unroll
    for (int j = 0; j < 4; j++) {
        int n = n0 + wn + j * 16 + lm;
        int rsn = rsum[n];
        float bn = bias[n];
#pragma unroll
        for (int i = 0; i < 4; i++) {
            int mb = m0 + wm + i * 16 + lq * 4;
#pragma unroll
            for (int rg = 0; rg < 4; rg++) {
                int v = acc[i][j][rg] - zx * rsn;
                float f = (float)v * s1 + bn;
                float g = f * 0.5f * (1.0f + erff(f * 0.7071067811865476f));
                _Float16 gh = (_Float16)g;
                H[(long)(mb + rg) * D_HID + n] = gh;
                float gf = (float)gh;
                lmin = fminf(lmin, gf);
                lmax = fmaxf(lmax, gf);
            }
        }
    }
    for (int off = 32; off > 0; off >>= 1) {
        lmin = fminf(lmin, __shfl_down(lmin, off));
        lmax = fmaxf(lmax, __shfl_down(lmax, off));
    }
    __syncthreads();
    float* red = (float*)As;
    if (lane == 0) { red[wave] = lmin; red[4 + wave] = lmax; }
    __syncthreads();
    if (tid == 0) {
        atomicMin(&slots[4], enc_f(fminf(fminf(red[0], red[1]), fminf(red[2], red[3]))));
        atomicMax(&slots[5], enc_f(fmaxf(fmaxf(red[4], red[5]), fmaxf(red[6], red[7]))));
    }
}

__global__ __launch_bounds__(256) void k_gemm2(const signed char* __restrict__ Aq,
                                               const signed char* __restrict__ Bq,
                                               float* __restrict__ Out,
                                               const float* __restrict__ scal,
                                               const int* __restrict__ iscal,
                                               const int* __restrict__ rsum,
                                               const float* __restrict__ bias) {
    __shared__ __align__(16) signed char As[128 * 64];
    __shared__ __align__(16) signed char Bs[128 * 64];
    const int nb = D_IN / 128;
    const int m0 = (blockIdx.x / nb) * 128, n0 = (blockIdx.x % nb) * 128;
    v4i acc[4][4];
    v4i zero = {0, 0, 0, 0};
#pragma unroll
    for (int i = 0; i < 4; i++)
#pragma unroll
        for (int j = 0; j < 4; j++) acc[i][j] = zero;
    int8_mainloop(Aq, Bq, D_HID, m0, n0, As, Bs, acc);

    const int tid = threadIdx.x, lane = tid & 63, wave = tid >> 6;
    const int wm = (wave & 1) << 6, wn = (wave >> 1) << 6;
    const int lm = lane & 15, lq = lane >> 4;
    float s2 = scal[7];
    int zx = iscal[1];
#pragma unroll
    for (int j = 0; j < 4; j++) {
        int n = n0 + wn + j * 16 + lm;
        int rsn = rsum[n];
        float bn = bias[n];
#pragma unroll
        for (int i = 0; i < 4; i++) {
            int mb = m0 + wm + i * 16 + lq * 4;
#pragma unroll
            for (int rg = 0; rg < 4; rg++) {
                int v = acc[i][j][rg] - zx * rsn;
                Out[(long)(mb + rg) * D_IN + n] = (float)v * s2 + bn;
            }
        }
    }
}

extern "C" void kernel_launch(void* const* d_in, const int* in_sizes, int n_in,
                              void* d_out, int out_size, void* d_ws, size_t ws_size,
                              hipStream_t stream) {
    const float* x  = (const float*)d_in[0];
    const float* W1 = (const float*)d_in[1];
    const float* b1 = (const float*)d_in[2];
    const float* W2 = (const float*)d_in[3];
    const float* b2 = (const float*)d_in[4];

    char* ws = (char*)d_ws;
    unsigned* slots    = (unsigned*)(ws + OFF_SLOTS);
    float* scal        = (float*)(ws + OFF_SCAL);
    int* iscal         = (int*)(ws + OFF_ISCAL);
    signed char* xq    = (signed char*)(ws + OFF_XQ);
    signed char* w1q   = (signed char*)(ws + OFF_W1Q);
    signed char* w2q   = (signed char*)(ws + OFF_W2Q);
    int* rs1           = (int*)(ws + OFF_RS1);
    int* rs2           = (int*)(ws + OFF_RS2);
    _Float16* h        = (_Float16*)(ws + OFF_H);
    signed char* hq    = (signed char*)(ws + OFF_HQ);

    k_init<<<1, 64, 0, stream>>>(slots);
    k_minmax<<<2048, 256, 0, stream>>>((const float4*)x, M_TOK * D_IN / 4, slots);
    k_absmax<<<512, 256, 0, stream>>>((const float4*)W1, D_HID * D_IN / 4, slots, 2);
    k_absmax<<<512, 256, 0, stream>>>((const float4*)W2, D_IN * D_HID / 4, slots, 3);
    k_scales1<<<1, 1, 0, stream>>>(slots, scal, iscal);
    k_quant_x<<<2048, 256, 0, stream>>>((const float4*)x, (int*)xq, M_TOK * D_IN / 4, scal);
    k_quant_w<<<D_HID, 256, 0, stream>>>(W1, w1q, rs1, D_IN, scal, 2);
    k_quant_w<<<D_IN, 256, 0, stream>>>(W2, w2q, rs2, D_HID, scal, 3);
    k_gemm1<<<(M_TOK / 128) * (D_HID / 128), 256, 0, stream>>>(xq, w1q, h, scal, iscal, rs1, b1, slots);
    k_scales2<<<1, 1, 0, stream>>>(slots, scal, iscal);
    k_quant_h<<<4096, 256, 0, stream>>>((const f16x8*)h, (int2*)hq, M_TOK * D_HID / 8, scal);
    k_gemm2<<<(M_TOK / 128) * (D_IN / 128), 256, 0, stream>>>(hq, w2q, (float*)d_out, scal, iscal, rs2, b2);
}

// Round 3
// 506.540 us; speedup vs baseline: 1.1608x; 1.1267x over previous
//
#include <hip/hip_runtime.h>
#include <hip/hip_bf16.h>
#include <math.h>

// Problem dims (fixed by reference setup_inputs)
#define D_IN   1024
#define D_HID  4096
#define M_TOK  16384   // 4 * 4096 tokens

typedef int v4i __attribute__((ext_vector_type(4)));
typedef _Float16 f16x8 __attribute__((ext_vector_type(8)));

typedef __attribute__((address_space(3))) unsigned int lds_u32;
typedef const __attribute__((address_space(1))) unsigned int glb_u32;

// async global->LDS, 16B per lane, wave-uniform LDS base + lane*16
__device__ inline void gload_lds16(const signed char* g, signed char* l) {
    __builtin_amdgcn_global_load_lds((glb_u32*)g, (lds_u32*)l, 16, 0, 0);
}

// Branchless erf, Abramowitz-Stegun 7.1.26, |eps| <= 1.5e-7 (<< fp16-h rounding).
// ~14 VALU ops, no divergence — replaces ROCm's branchy libm erff (~50 ops).
__device__ inline float fast_erf(float x) {
    float ax = fabsf(x);
    float t = __builtin_amdgcn_rcpf(fmaf(0.3275911f, ax, 1.0f));
    float y = t * (0.254829592f +
              t * (-0.284496736f +
              t * (1.421413741f +
              t * (-1.453152027f +
              t * 1.061405429f))));
    float e = __expf(-ax * ax);          // native v_exp path
    float r = fmaf(-y, e, 1.0f);
    return copysignf(r, x);
}

// ---------------- workspace layout (bytes) ----------------
#define OFF_SLOTS  ((size_t)0)                                   // 8 x u32 atomic slots
#define OFF_SCAL   ((size_t)64)                                  // 16 x f32 scalars
#define OFF_ISCAL  ((size_t)128)                                 // 8 x i32
#define OFF_XQ     ((size_t)256)                                 // 16M  int8
#define OFF_W1Q    (OFF_XQ  + (size_t)M_TOK * D_IN)              // 4M   int8
#define OFF_W2Q    (OFF_W1Q + (size_t)D_HID * D_IN)              // 4M   int8
#define OFF_RS1    (OFF_W2Q + (size_t)D_IN * D_HID)              // 16K  i32
#define OFF_RS2    (OFF_RS1 + (size_t)D_HID * 4)                 // 4K   i32
#define OFF_H      (OFF_RS2 + (size_t)D_IN * 4 + 128)            // 128M fp16
#define OFF_HQ     (OFF_H   + (size_t)M_TOK * D_HID * 2)         // 64M  int8
// total ~226.5 MB

// slots: [0] x min(enc) [1] x max(enc) [2] |W1|max bits [3] |W2|max bits
//        [4] h min(enc) [5] h max(enc)
// scal:  [0] sx1 [1] zx1f [2] sw1 [3] sw2 [4] s1=sx1*sw1 [5] sx2 [6] zx2f [7] s2=sx2*sw2
// iscal: [0] zx1 [1] zx2

__device__ inline unsigned enc_f(float f) {
    unsigned u = __float_as_uint(f);
    return (u & 0x80000000u) ? ~u : (u | 0x80000000u);
}
__device__ inline float dec_f(unsigned u) {
    return __uint_as_float((u & 0x80000000u) ? (u ^ 0x80000000u) : ~u);
}

__global__ void k_init(unsigned* slots) {
    int t = threadIdx.x;
    if (t < 8) slots[t] = (t == 0 || t == 4) ? 0xFFFFFFFFu : 0u;
}

__global__ void k_minmax(const float4* __restrict__ x, int n4, unsigned* slots) {
    float vmin = 3.4e38f, vmax = -3.4e38f;
    for (int i = blockIdx.x * blockDim.x + threadIdx.x; i < n4; i += gridDim.x * blockDim.x) {
        float4 v = x[i];
        vmin = fminf(vmin, fminf(fminf(v.x, v.y), fminf(v.z, v.w)));
        vmax = fmaxf(vmax, fmaxf(fmaxf(v.x, v.y), fmaxf(v.z, v.w)));
    }
    for (int off = 32; off > 0; off >>= 1) {
        vmin = fminf(vmin, __shfl_down(vmin, off));
        vmax = fmaxf(vmax, __shfl_down(vmax, off));
    }
    __shared__ float red[8];
    int wave = threadIdx.x >> 6, lane = threadIdx.x & 63;
    if (lane == 0) { red[wave] = vmin; red[4 + wave] = vmax; }
    __syncthreads();
    if (threadIdx.x == 0) {
        float bmin = fminf(fminf(red[0], red[1]), fminf(red[2], red[3]));
        float bmax = fmaxf(fmaxf(red[4], red[5]), fmaxf(red[6], red[7]));
        atomicMin(&slots[0], enc_f(bmin));
        atomicMax(&slots[1], enc_f(bmax));
    }
}

__global__ void k_absmax(const float4* __restrict__ w, int n4, unsigned* slots, int slot) {
    float vmax = 0.0f;
    for (int i = blockIdx.x * blockDim.x + threadIdx.x; i < n4; i += gridDim.x * blockDim.x) {
        float4 v = w[i];
        vmax = fmaxf(vmax, fmaxf(fmaxf(fabsf(v.x), fabsf(v.y)), fmaxf(fabsf(v.z), fabsf(v.w))));
    }
    for (int off = 32; off > 0; off >>= 1)
        vmax = fmaxf(vmax, __shfl_down(vmax, off));
    __shared__ float red[4];
    int wave = threadIdx.x >> 6, lane = threadIdx.x & 63;
    if (lane == 0) red[wave] = vmax;
    __syncthreads();
    if (threadIdx.x == 0) {
        float bmax = fmaxf(fmaxf(red[0], red[1]), fmaxf(red[2], red[3]));
        atomicMax(&slots[slot], __float_as_uint(bmax));  // bmax >= 0: raw bits monotone
    }
}

__global__ void k_scales1(const unsigned* slots, float* scal, int* iscal) {
    float amin = dec_f(slots[0]), amax = dec_f(slots[1]);
    float sx = fmaxf((amax - amin) / 255.0f, 1e-8f);
    float zx = rintf(-amin / sx) - 128.0f;
    zx = fminf(fmaxf(zx, -128.0f), 127.0f);
    float sw1 = fmaxf(__uint_as_float(slots[2]) / 127.0f, 1e-8f);
    float sw2 = fmaxf(__uint_as_float(slots[3]) / 127.0f, 1e-8f);
    scal[0] = sx; scal[1] = zx; scal[2] = sw1; scal[3] = sw2; scal[4] = sx * sw1;
    iscal[0] = (int)zx;
}

__global__ void k_scales2(const unsigned* slots, float* scal, int* iscal) {
    float amin = dec_f(slots[4]), amax = dec_f(slots[5]);
    float s = fmaxf((amax - amin) / 255.0f, 1e-8f);
    float zp = rintf(-amin / s) - 128.0f;
    zp = fminf(fmaxf(zp, -128.0f), 127.0f);
    scal[5] = s; scal[6] = zp; scal[7] = s * scal[3];
    iscal[1] = (int)zp;
}

__global__ void k_quant_x(const float4* __restrict__ x, int* __restrict__ xq, int n4,
                          const float* __restrict__ scal) {
    float s = scal[0], zp = scal[1];
    for (int i = blockIdx.x * blockDim.x + threadIdx.x; i < n4; i += gridDim.x * blockDim.x) {
        float4 v = x[i];
        int a = (int)fminf(fmaxf(rintf(v.x / s) + zp, -128.0f), 127.0f);
        int b = (int)fminf(fmaxf(rintf(v.y / s) + zp, -128.0f), 127.0f);
        int c = (int)fminf(fmaxf(rintf(v.z / s) + zp, -128.0f), 127.0f);
        int d = (int)fminf(fmaxf(rintf(v.w / s) + zp, -128.0f), 127.0f);
        xq[i] = (a & 255) | ((b & 255) << 8) | ((c & 255) << 16) | ((d & 255) << 24);
    }
}

// one block per weight row: quantize + row sum
__global__ void k_quant_w(const float* __restrict__ W, signed char* __restrict__ Wq,
                          int* __restrict__ rsum, int K, const float* __restrict__ scal, int sslot) {
    float s = scal[sslot];
    int row = blockIdx.x;
    const float4* Wr = (const float4*)(W + (size_t)row * K);
    int* out = (int*)(Wq + (size_t)row * K);
    int mysum = 0;
    for (int i = threadIdx.x; i < K / 4; i += blockDim.x) {
        float4 v = Wr[i];
        int a = (int)fminf(fmaxf(rintf(v.x / s), -127.0f), 127.0f);
        int b = (int)fminf(fmaxf(rintf(v.y / s), -127.0f), 127.0f);
        int c = (int)fminf(fmaxf(rintf(v.z / s), -127.0f), 127.0f);
        int d = (int)fminf(fmaxf(rintf(v.w / s), -127.0f), 127.0f);
        mysum += a + b + c + d;
        out[i] = (a & 255) | ((b & 255) << 8) | ((c & 255) << 16) | ((d & 255) << 24);
    }
    for (int off = 32; off > 0; off >>= 1)
        mysum += __shfl_down(mysum, off);
    __shared__ int red[4];
    int wave = threadIdx.x >> 6, lane = threadIdx.x & 63;
    if (lane == 0) red[wave] = mysum;
    __syncthreads();
    if (threadIdx.x == 0) rsum[row] = red[0] + red[1] + red[2] + red[3];
}

__global__ void k_quant_h(const f16x8* __restrict__ H, int2* __restrict__ Hq, int n8,
                          const float* __restrict__ scal) {
    float s = scal[5], zp = scal[6];
    for (int i = blockIdx.x * blockDim.x + threadIdx.x; i < n8; i += gridDim.x * blockDim.x) {
        f16x8 v = H[i];
        int q[8];
#pragma unroll
        for (int j = 0; j < 8; j++)
            q[j] = ((int)fminf(fmaxf(rintf((float)v[j] / s) + zp, -128.0f), 127.0f)) & 255;
        int lo = q[0] | (q[1] << 8) | (q[2] << 16) | (q[3] << 24);
        int hi = q[4] | (q[5] << 8) | (q[6] << 16) | (q[7] << 24);
        Hq[i] = make_int2(lo, hi);
    }
}

// ---------------- int8 MFMA GEMM mainloop ----------------
// C[m][n] = sum_k A[m][k] * B[n][k]   (both row-major, K contiguous)
// 128x128 tile, BK=128 per barrier (two BK=64 sub-stages in separate LDS
// regions, identical proven-0-conflict layout), 256 threads, 2x2 wave grid,
// 4x4 16x16x64 tiles/wave, 32 MFMA per barrier-drain (m97-class amortization).
// Staging: global_load_lds width=16. Swizzle: chunk (row,c) holds global chunk
// c ^ ((row>>1)&3); reader f = lq ^ ((lm>>1)&3). SQ_LDS_BANK_CONFLICT = 0 (R2).
__device__ inline void int8_mainloop(const signed char* __restrict__ A,
                                     const signed char* __restrict__ B,
                                     int K, int m0, int n0,
                                     signed char* As, signed char* Bs, v4i acc[4][4]) {
    const int tid = threadIdx.x;
    const int lane = tid & 63, wave = tid >> 6;
    const int wm = (wave & 1) << 6, wn = (wave >> 1) << 6;
    const int lm = lane & 15, lq = lane >> 4;

    // staging assignment: wave w stages rows [w*32, w*32+32), 16B/lane
    const int r0 = wave * 32 + (lane >> 2);      // rows w*32 .. +15
    const int r1 = r0 + 16;                      // rows w*32+16 .. +31
    const int c  = lane & 3;
    const int col0 = c ^ ((r0 >> 1) & 3);
    const int col1 = c ^ ((r1 >> 1) & 3);

    const signed char* gA0 = A + (long)(m0 + r0) * K + col0 * 16;
    const signed char* gA1 = A + (long)(m0 + r1) * K + col1 * 16;
    const signed char* gB0 = B + (long)(n0 + r0) * K + col0 * 16;
    const signed char* gB1 = B + (long)(n0 + r1) * K + col1 * 16;
    signed char* lA0 = As + (wave * 32) * 64 + lane * 16;
    signed char* lA1 = As + (wave * 32 + 16) * 64 + lane * 16;
    signed char* lB0 = Bs + (wave * 32) * 64 + lane * 16;
    signed char* lB1 = Bs + (wave * 32 + 16) * 64 + lane * 16;

    // fragment-read swizzle, independent of tile index i
    const int f = lq ^ ((lm >> 1) & 3);

    for (int k0 = 0; k0 < K; k0 += 128) {
        __syncthreads();
        // k-half 0 -> region 0
        gload_lds16(gA0,      lA0);
        gload_lds16(gA1,      lA1);
        gload_lds16(gB0,      lB0);
        gload_lds16(gB1,      lB1);
        // k-half 1 -> region 1 (LDS offset 8192)
        gload_lds16(gA0 + 64, lA0 + 8192);
        gload_lds16(gA1 + 64, lA1 + 8192);
        gload_lds16(gB0 + 64, lB0 + 8192);
        gload_lds16(gB1 + 64, lB1 + 8192);
        gA0 += 128; gA1 += 128; gB0 += 128; gB1 += 128;
        asm volatile("s_waitcnt vmcnt(0)" ::: "memory");
        __syncthreads();
#pragma unroll
        for (int h = 0; h < 2; h++) {
            const int base = h * 8192;
            v4i av[4], bv[4];
#pragma unroll
            for (int i = 0; i < 4; i++)
                av[i] = *(const v4i*)&As[base + (wm + i * 16 + lm) * 64 + f * 16];
#pragma unroll
            for (int j = 0; j < 4; j++)
                bv[j] = *(const v4i*)&Bs[base + (wn + j * 16 + lm) * 64 + f * 16];
#pragma unroll
            for (int i = 0; i < 4; i++)
#pragma unroll
                for (int j = 0; j < 4; j++)
                    acc[i][j] = __builtin_amdgcn_mfma_i32_16x16x64_i8(av[i], bv[j], acc[i][j], 0, 0, 0);
        }
    }
}

__global__ __launch_bounds__(256) void k_gemm1(const signed char* __restrict__ Aq,
                                               const signed char* __restrict__ Bq,
                                               _Float16* __restrict__ H,
                                               const float* __restrict__ scal,
                                               const int* __restrict__ iscal,
                                               const int* __restrict__ rsum,
                                               const float* __restrict__ bias,
                                               unsigned* slots) {
    __shared__ __align__(16) signed char As[2 * 128 * 64];
    __shared__ __align__(16) signed char Bs[2 * 128 * 64];
    const int nb = D_HID / 128;
    const int m0 = (blockIdx.x / nb) * 128, n0 = (blockIdx.x % nb) * 128;
    v4i acc[4][4];
    v4i zero = {0, 0, 0, 0};
#pragma unroll
    for (int i = 0; i < 4; i++)
#pragma unroll
        for (int j = 0; j < 4; j++) acc[i][j] = zero;
    int8_mainloop(Aq, Bq, D_IN, m0, n0, As, Bs, acc);

    const int tid = threadIdx.x, lane = tid & 63, wave = tid >> 6;
    const int wm = (wave & 1) << 6, wn = (wave >> 1) << 6;
    const int lm = lane & 15, lq = lane >> 4;
    float s1 = scal[4];
    int zx = iscal[0];
    float lmin = 3.4e38f, lmax = -3.4e38f;
#pragma unroll
    for (int j = 0; j < 4; j++) {
        int n = n0 + wn + j * 16 + lm;
        int rsn = rsum[n];
        float bn = bias[n];
#pragma unroll
        for (int i = 0; i < 4; i++) {
            int mb = m0 + wm + i * 16 + lq * 4;
#pragma unroll
            for (int rg = 0; rg < 4; rg++) {
                int v = acc[i][j][rg] - zx * rsn;
                float fv = (float)v * s1 + bn;
                float g = fv * 0.5f * (1.0f + fast_erf(fv * 0.7071067811865476f));
                _Float16 gh = (_Float16)g;
                H[(long)(mb + rg) * D_HID + n] = gh;
                float gf = (float)gh;
                lmin = fminf(lmin, gf);
                lmax = fmaxf(lmax, gf);
            }
        }
    }
    for (int off = 32; off > 0; off >>= 1) {
        lmin = fminf(lmin, __shfl_down(lmin, off));
        lmax = fmaxf(lmax, __shfl_down(lmax, off));
    }
    __syncthreads();
    float* red = (float*)As;
    if (lane == 0) { red[wave] = lmin; red[4 + wave] = lmax; }
    __syncthreads();
    if (tid == 0) {
        atomicMin(&slots[4], enc_f(fminf(fminf(red[0], red[1]), fminf(red[2], red[3]))));
        atomicMax(&slots[5], enc_f(fmaxf(fmaxf(red[4], red[5]), fmaxf(red[6], red[7]))));
    }
}

__global__ __launch_bounds__(256) void k_gemm2(const signed char* __restrict__ Aq,
                                               const signed char* __restrict__ Bq,
                                               float* __restrict__ Out,
                                               const float* __restrict__ scal,
                                               const int* __restrict__ iscal,
                                               const int* __restrict__ rsum,
                                               const float* __restrict__ bias) {
    __shared__ __align__(16) signed char As[2 * 128 * 64];
    __shared__ __align__(16) signed char Bs[2 * 128 * 64];
    const int nb = D_IN / 128;
    const int m0 = (blockIdx.x / nb) * 128, n0 = (blockIdx.x % nb) * 128;
    v4i acc[4][4];
    v4i zero = {0, 0, 0, 0};
#pragma unroll
    for (int i = 0; i < 4; i++)
#pragma unroll
        for (int j = 0; j < 4; j++) acc[i][j] = zero;
    int8_mainloop(Aq, Bq, D_HID, m0, n0, As, Bs, acc);

    const int tid = threadIdx.x, lane = tid & 63, wave = tid >> 6;
    const int wm = (wave & 1) << 6, wn = (wave >> 1) << 6;
    const int lm = lane & 15, lq = lane >> 4;
    float s2 = scal[7];
    int zx = iscal[1];
#pragma unroll
    for (int j = 0; j < 4; j++) {
        int n = n0 + wn + j * 16 + lm;
        int rsn = rsum[n];
        float bn = bias[n];
#pragma unroll
        for (int i = 0; i < 4; i++) {
            int mb = m0 + wm + i * 16 + lq * 4;
#pragma unroll
            for (int rg = 0; rg < 4; rg++) {
                int v = acc[i][j][rg] - zx * rsn;
                Out[(long)(mb + rg) * D_IN + n] = (float)v * s2 + bn;
            }
        }
    }
}

extern "C" void kernel_launch(void* const* d_in, const int* in_sizes, int n_in,
                              void* d_out, int out_size, void* d_ws, size_t ws_size,
                              hipStream_t stream) {
    const float* x  = (const float*)d_in[0];
    const float* W1 = (const float*)d_in[1];
    const float* b1 = (const float*)d_in[2];
    const float* W2 = (const float*)d_in[3];
    const float* b2 = (const float*)d_in[4];

    char* ws = (char*)d_ws;
    unsigned* slots    = (unsigned*)(ws + OFF_SLOTS);
    float* scal        = (float*)(ws + OFF_SCAL);
    int* iscal         = (int*)(ws + OFF_ISCAL);
    signed char* xq    = (signed char*)(ws + OFF_XQ);
    signed char* w1q   = (signed char*)(ws + OFF_W1Q);
    signed char* w2q   = (signed char*)(ws + OFF_W2Q);
    int* rs1           = (int*)(ws + OFF_RS1);
    int* rs2           = (int*)(ws + OFF_RS2);
    _Float16* h        = (_Float16*)(ws + OFF_H);
    signed char* hq    = (signed char*)(ws + OFF_HQ);

    k_init<<<1, 64, 0, stream>>>(slots);
    k_minmax<<<2048, 256, 0, stream>>>((const float4*)x, M_TOK * D_IN / 4, slots);
    k_absmax<<<512, 256, 0, stream>>>((const float4*)W1, D_HID * D_IN / 4, slots, 2);
    k_absmax<<<512, 256, 0, stream>>>((const float4*)W2, D_IN * D_HID / 4, slots, 3);
    k_scales1<<<1, 1, 0, stream>>>(slots, scal, iscal);
    k_quant_x<<<2048, 256, 0, stream>>>((const float4*)x, (int*)xq, M_TOK * D_IN / 4, scal);
    k_quant_w<<<D_HID, 256, 0, stream>>>(W1, w1q, rs1, D_IN, scal, 2);
    k_quant_w<<<D_IN, 256, 0, stream>>>(W2, w2q, rs2, D_HID, scal, 3);
    k_gemm1<<<(M_TOK / 128) * (D_HID / 128), 256, 0, stream>>>(xq, w1q, h, scal, iscal, rs1, b1, slots);
    k_scales2<<<1, 1, 0, stream>>>(slots, scal, iscal);
    k_quant_h<<<4096, 256, 0, stream>>>((const f16x8*)h, (int2*)hq, M_TOK * D_HID / 8, scal);
    k_gemm2<<<(M_TOK / 128) * (D_IN / 128), 256, 0, stream>>>(hq, w2q, (float*)d_out, scal, iscal, rs2, b2);
}

// Round 4
// 505.377 us; speedup vs baseline: 1.1635x; 1.0023x over previous
//
#include <hip/hip_runtime.h>
#include <hip/hip_bf16.h>
#include <math.h>

// Problem dims (fixed by reference setup_inputs)
#define D_IN   1024
#define D_HID  4096
#define M_TOK  16384   // 4 * 4096 tokens

typedef int v4i __attribute__((ext_vector_type(4)));
typedef _Float16 f16x8 __attribute__((ext_vector_type(8)));

typedef __attribute__((address_space(3))) unsigned int lds_u32;
typedef const __attribute__((address_space(1))) unsigned int glb_u32;

// async global->LDS, 16B per lane, wave-uniform LDS base + lane*16
__device__ inline void gload_lds16(const signed char* g, signed char* l) {
    __builtin_amdgcn_global_load_lds((glb_u32*)g, (lds_u32*)l, 16, 0, 0);
}

// Branchless erf, Abramowitz-Stegun 7.1.26, |eps| <= 1.5e-7 (<< fp16-h rounding).
__device__ inline float fast_erf(float x) {
    float ax = fabsf(x);
    float t = __builtin_amdgcn_rcpf(fmaf(0.3275911f, ax, 1.0f));
    float y = t * (0.254829592f +
              t * (-0.284496736f +
              t * (1.421413741f +
              t * (-1.453152027f +
              t * 1.061405429f))));
    float e = __expf(-ax * ax);          // native v_exp path
    float r = fmaf(-y, e, 1.0f);
    return copysignf(r, x);
}

// ---------------- workspace layout (bytes) ----------------
#define OFF_SLOTS  ((size_t)0)                                   // 8 x u32 atomic slots
#define OFF_SCAL   ((size_t)64)                                  // 16 x f32 scalars
#define OFF_ISCAL  ((size_t)128)                                 // 8 x i32
#define OFF_XQ     ((size_t)256)                                 // 16M  int8
#define OFF_W1Q    (OFF_XQ  + (size_t)M_TOK * D_IN)              // 4M   int8
#define OFF_W2Q    (OFF_W1Q + (size_t)D_HID * D_IN)              // 4M   int8
#define OFF_RS1    (OFF_W2Q + (size_t)D_IN * D_HID)              // 16K  i32
#define OFF_RS2    (OFF_RS1 + (size_t)D_HID * 4)                 // 4K   i32
#define OFF_H      (OFF_RS2 + (size_t)D_IN * 4 + 128)            // 128M fp16
#define OFF_HQ     (OFF_H   + (size_t)M_TOK * D_HID * 2)         // 64M  int8
// total ~226.5 MB

// slots: [0] x min(enc) [1] x max(enc) [2] |W1|max bits [3] |W2|max bits
//        [4] h min(enc) [5] h max(enc)
// scal:  [0] sx1 [1] zx1f [2] sw1 [3] sw2 [4] s1=sx1*sw1 [5] sx2 [6] zx2f [7] s2=sx2*sw2
// iscal: [0] zx1 [1] zx2

__device__ inline unsigned enc_f(float f) {
    unsigned u = __float_as_uint(f);
    return (u & 0x80000000u) ? ~u : (u | 0x80000000u);
}
__device__ inline float dec_f(unsigned u) {
    return __uint_as_float((u & 0x80000000u) ? (u ^ 0x80000000u) : ~u);
}

__global__ void k_init(unsigned* slots) {
    int t = threadIdx.x;
    if (t < 8) slots[t] = (t == 0 || t == 4) ? 0xFFFFFFFFu : 0u;
}

__global__ void k_minmax(const float4* __restrict__ x, int n4, unsigned* slots) {
    float vmin = 3.4e38f, vmax = -3.4e38f;
    for (int i = blockIdx.x * blockDim.x + threadIdx.x; i < n4; i += gridDim.x * blockDim.x) {
        float4 v = x[i];
        vmin = fminf(vmin, fminf(fminf(v.x, v.y), fminf(v.z, v.w)));
        vmax = fmaxf(vmax, fmaxf(fmaxf(v.x, v.y), fmaxf(v.z, v.w)));
    }
    for (int off = 32; off > 0; off >>= 1) {
        vmin = fminf(vmin, __shfl_down(vmin, off));
        vmax = fmaxf(vmax, __shfl_down(vmax, off));
    }
    __shared__ float red[8];
    int wave = threadIdx.x >> 6, lane = threadIdx.x & 63;
    if (lane == 0) { red[wave] = vmin; red[4 + wave] = vmax; }
    __syncthreads();
    if (threadIdx.x == 0) {
        float bmin = fminf(fminf(red[0], red[1]), fminf(red[2], red[3]));
        float bmax = fmaxf(fmaxf(red[4], red[5]), fmaxf(red[6], red[7]));
        atomicMin(&slots[0], enc_f(bmin));
        atomicMax(&slots[1], enc_f(bmax));
    }
}

__global__ void k_absmax(const float4* __restrict__ w, int n4, unsigned* slots, int slot) {
    float vmax = 0.0f;
    for (int i = blockIdx.x * blockDim.x + threadIdx.x; i < n4; i += gridDim.x * blockDim.x) {
        float4 v = w[i];
        vmax = fmaxf(vmax, fmaxf(fmaxf(fabsf(v.x), fabsf(v.y)), fmaxf(fabsf(v.z), fabsf(v.w))));
    }
    for (int off = 32; off > 0; off >>= 1)
        vmax = fmaxf(vmax, __shfl_down(vmax, off));
    __shared__ float red[4];
    int wave = threadIdx.x >> 6, lane = threadIdx.x & 63;
    if (lane == 0) red[wave] = vmax;
    __syncthreads();
    if (threadIdx.x == 0) {
        float bmax = fmaxf(fmaxf(red[0], red[1]), fmaxf(red[2], red[3]));
        atomicMax(&slots[slot], __float_as_uint(bmax));  // bmax >= 0: raw bits monotone
    }
}

__global__ void k_scales1(const unsigned* slots, float* scal, int* iscal) {
    float amin = dec_f(slots[0]), amax = dec_f(slots[1]);
    float sx = fmaxf((amax - amin) / 255.0f, 1e-8f);
    float zx = rintf(-amin / sx) - 128.0f;
    zx = fminf(fmaxf(zx, -128.0f), 127.0f);
    float sw1 = fmaxf(__uint_as_float(slots[2]) / 127.0f, 1e-8f);
    float sw2 = fmaxf(__uint_as_float(slots[3]) / 127.0f, 1e-8f);
    scal[0] = sx; scal[1] = zx; scal[2] = sw1; scal[3] = sw2; scal[4] = sx * sw1;
    iscal[0] = (int)zx;
}

__global__ void k_scales2(const unsigned* slots, float* scal, int* iscal) {
    float amin = dec_f(slots[4]), amax = dec_f(slots[5]);
    float s = fmaxf((amax - amin) / 255.0f, 1e-8f);
    float zp = rintf(-amin / s) - 128.0f;
    zp = fminf(fmaxf(zp, -128.0f), 127.0f);
    scal[5] = s; scal[6] = zp; scal[7] = s * scal[3];
    iscal[1] = (int)zp;
}

__global__ void k_quant_x(const float4* __restrict__ x, int* __restrict__ xq, int n4,
                          const float* __restrict__ scal) {
    float s = scal[0], zp = scal[1];
    for (int i = blockIdx.x * blockDim.x + threadIdx.x; i < n4; i += gridDim.x * blockDim.x) {
        float4 v = x[i];
        int a = (int)fminf(fmaxf(rintf(v.x / s) + zp, -128.0f), 127.0f);
        int b = (int)fminf(fmaxf(rintf(v.y / s) + zp, -128.0f), 127.0f);
        int c = (int)fminf(fmaxf(rintf(v.z / s) + zp, -128.0f), 127.0f);
        int d = (int)fminf(fmaxf(rintf(v.w / s) + zp, -128.0f), 127.0f);
        xq[i] = (a & 255) | ((b & 255) << 8) | ((c & 255) << 16) | ((d & 255) << 24);
    }
}

// one block per weight row: quantize + row sum
__global__ void k_quant_w(const float* __restrict__ W, signed char* __restrict__ Wq,
                          int* __restrict__ rsum, int K, const float* __restrict__ scal, int sslot) {
    float s = scal[sslot];
    int row = blockIdx.x;
    const float4* Wr = (const float4*)(W + (size_t)row * K);
    int* out = (int*)(Wq + (size_t)row * K);
    int mysum = 0;
    for (int i = threadIdx.x; i < K / 4; i += blockDim.x) {
        float4 v = Wr[i];
        int a = (int)fminf(fmaxf(rintf(v.x / s), -127.0f), 127.0f);
        int b = (int)fminf(fmaxf(rintf(v.y / s), -127.0f), 127.0f);
        int c = (int)fminf(fmaxf(rintf(v.z / s), -127.0f), 127.0f);
        int d = (int)fminf(fmaxf(rintf(v.w / s), -127.0f), 127.0f);
        mysum += a + b + c + d;
        out[i] = (a & 255) | ((b & 255) << 8) | ((c & 255) << 16) | ((d & 255) << 24);
    }
    for (int off = 32; off > 0; off >>= 1)
        mysum += __shfl_down(mysum, off);
    __shared__ int red[4];
    int wave = threadIdx.x >> 6, lane = threadIdx.x & 63;
    if (lane == 0) red[wave] = mysum;
    __syncthreads();
    if (threadIdx.x == 0) rsum[row] = red[0] + red[1] + red[2] + red[3];
}

__global__ void k_quant_h(const f16x8* __restrict__ H, int2* __restrict__ Hq, int n8,
                          const float* __restrict__ scal) {
    float s = scal[5], zp = scal[6];
    for (int i = blockIdx.x * blockDim.x + threadIdx.x; i < n8; i += gridDim.x * blockDim.x) {
        f16x8 v = H[i];
        int q[8];
#pragma unroll
        for (int j = 0; j < 8; j++)
            q[j] = ((int)fminf(fmaxf(rintf((float)v[j] / s) + zp, -128.0f), 127.0f)) & 255;
        int lo = q[0] | (q[1] << 8) | (q[2] << 16) | (q[3] << 24);
        int hi = q[4] | (q[5] << 8) | (q[6] << 16) | (q[7] << 24);
        Hq[i] = make_int2(lo, hi);
    }
}

// ---------------- int8 MFMA GEMM mainloop ----------------
// C[m][n] = sum_k A[m][k] * B[n][k]   (both row-major, K contiguous)
// 128x128 tile, 256 threads, 2x2 wave grid, 4x4 16x16x64 tiles/wave.
// SOFTWARE-PIPELINED double buffer (AITER-style, never vmcnt(0) mid-loop):
//   stage s+1 DMA -> buf[1-cur]; s_waitcnt vmcnt(4) (drains only stage s's 4
//   oldest DMAs); raw s_barrier; compute buf[cur]; raw s_barrier.
// Raw asm barriers bypass the compiler's forced vmcnt(0)-before-__syncthreads
// (the ~100us drain identified in R3). Buffer safety: barrier #2 guarantees
// all waves consumed buf[cur] before the next iteration's DMA overwrites it.
// Swizzle: chunk (row,c) holds global chunk c ^ ((row>>1)&3); reader
// f = lq ^ ((lm>>1)&3). SQ_LDS_BANK_CONFLICT = 0 (verified R2/R3).
__device__ inline void int8_mainloop(const signed char* __restrict__ A,
                                     const signed char* __restrict__ B,
                                     int K, int m0, int n0,
                                     signed char* As, signed char* Bs, v4i acc[4][4]) {
    const int tid = threadIdx.x;
    const int lane = tid & 63, wave = tid >> 6;
    const int wm = (wave & 1) << 6, wn = (wave >> 1) << 6;
    const int lm = lane & 15, lq = lane >> 4;

    // staging assignment: wave w stages rows [w*32, w*32+32), 16B/lane
    const int r0 = wave * 32 + (lane >> 2);      // rows w*32 .. +15
    const int r1 = r0 + 16;                      // rows w*32+16 .. +31
    const int c  = lane & 3;
    const int col0 = c ^ ((r0 >> 1) & 3);
    const int col1 = c ^ ((r1 >> 1) & 3);

    const signed char* gA0 = A + (long)(m0 + r0) * K + col0 * 16;
    const signed char* gA1 = A + (long)(m0 + r1) * K + col1 * 16;
    const signed char* gB0 = B + (long)(n0 + r0) * K + col0 * 16;
    const signed char* gB1 = B + (long)(n0 + r1) * K + col1 * 16;
    signed char* lA0 = As + (wave * 32) * 64 + lane * 16;
    signed char* lA1 = lA0 + 16 * 64;
    signed char* lB0 = Bs + (wave * 32) * 64 + lane * 16;
    signed char* lB1 = lB0 + 16 * 64;

    // fragment-read swizzle, independent of tile index i
    const int f = lq ^ ((lm >> 1) & 3);
    const int S = K >> 6;   // BK=64 stages (16 for K=1024, 64 for K=4096)

    // prologue: stage 0 -> buffer 0
    gload_lds16(gA0, lA0);
    gload_lds16(gA1, lA1);
    gload_lds16(gB0, lB0);
    gload_lds16(gB1, lB1);

#pragma unroll 2
    for (int s = 0; s < S; s++) {
        const int cur = (s & 1) * 8192;
        const int nxt = 8192 - cur;
        if (s + 1 < S) {
            const long go = (long)(s + 1) * 64;
            gload_lds16(gA0 + go, lA0 + nxt);
            gload_lds16(gA1 + go, lA1 + nxt);
            gload_lds16(gB0 + go, lB0 + nxt);
            gload_lds16(gB1 + go, lB1 + nxt);
            // wait only for stage s's 4 oldest DMAs; stage s+1 stays in flight
            asm volatile("s_waitcnt vmcnt(4)\n\ts_barrier" ::: "memory");
        } else {
            asm volatile("s_waitcnt vmcnt(0)\n\ts_barrier" ::: "memory");
        }
        v4i av[4], bv[4];
#pragma unroll
        for (int i = 0; i < 4; i++)
            av[i] = *(const v4i*)&As[cur + (wm + i * 16 + lm) * 64 + f * 16];
#pragma unroll
        for (int j = 0; j < 4; j++)
            bv[j] = *(const v4i*)&Bs[cur + (wn + j * 16 + lm) * 64 + f * 16];
#pragma unroll
        for (int i = 0; i < 4; i++)
#pragma unroll
            for (int j = 0; j < 4; j++)
                acc[i][j] = __builtin_amdgcn_mfma_i32_16x16x64_i8(av[i], bv[j], acc[i][j], 0, 0, 0);
        // all waves done reading buf[cur] (ds_read data consumed by MFMA issue)
        // before next iteration's DMA may overwrite it
        asm volatile("s_barrier" ::: "memory");
    }
}

__global__ __launch_bounds__(256) void k_gemm1(const signed char* __restrict__ Aq,
                                               const signed char* __restrict__ Bq,
                                               _Float16* __restrict__ H,
                                               const float* __restrict__ scal,
                                               const int* __restrict__ iscal,
                                               const int* __restrict__ rsum,
                                               const float* __restrict__ bias,
                                               unsigned* slots) {
    __shared__ __align__(16) signed char As[2 * 128 * 64];
    __shared__ __align__(16) signed char Bs[2 * 128 * 64];
    const int nb = D_HID / 128;
    const int m0 = (blockIdx.x / nb) * 128, n0 = (blockIdx.x % nb) * 128;
    v4i acc[4][4];
    v4i zero = {0, 0, 0, 0};
#pragma unroll
    for (int i = 0; i < 4; i++)
#pragma unroll
        for (int j = 0; j < 4; j++) acc[i][j] = zero;
    int8_mainloop(Aq, Bq, D_IN, m0, n0, As, Bs, acc);

    const int tid = threadIdx.x, lane = tid & 63, wave = tid >> 6;
    const int wm = (wave & 1) << 6, wn = (wave >> 1) << 6;
    const int lm = lane & 15, lq = lane >> 4;
    float s1 = scal[4];
    int zx = iscal[0];
    float lmin = 3.4e38f, lmax = -3.4e38f;
#pragma unroll
    for (int j = 0; j < 4; j++) {
        int n = n0 + wn + j * 16 + lm;
        int rsn = rsum[n];
        float bn = bias[n];
#pragma unroll
        for (int i = 0; i < 4; i++) {
            int mb = m0 + wm + i * 16 + lq * 4;
#pragma unroll
            for (int rg = 0; rg < 4; rg++) {
                int v = acc[i][j][rg] - zx * rsn;
                float fv = (float)v * s1 + bn;
                float g = fv * 0.5f * (1.0f + fast_erf(fv * 0.7071067811865476f));
                _Float16 gh = (_Float16)g;
                H[(long)(mb + rg) * D_HID + n] = gh;
                float gf = (float)gh;
                lmin = fminf(lmin, gf);
                lmax = fmaxf(lmax, gf);
            }
        }
    }
    for (int off = 32; off > 0; off >>= 1) {
        lmin = fminf(lmin, __shfl_down(lmin, off));
        lmax = fmaxf(lmax, __shfl_down(lmax, off));
    }
    __syncthreads();
    float* red = (float*)As;
    if (lane == 0) { red[wave] = lmin; red[4 + wave] = lmax; }
    __syncthreads();
    if (tid == 0) {
        atomicMin(&slots[4], enc_f(fminf(fminf(red[0], red[1]), fminf(red[2], red[3]))));
        atomicMax(&slots[5], enc_f(fmaxf(fmaxf(red[4], red[5]), fmaxf(red[6], red[7]))));
    }
}

__global__ __launch_bounds__(256) void k_gemm2(const signed char* __restrict__ Aq,
                                               const signed char* __restrict__ Bq,
                                               float* __restrict__ Out,
                                               const float* __restrict__ scal,
                                               const int* __restrict__ iscal,
                                               const int* __restrict__ rsum,
                                               const float* __restrict__ bias) {
    __shared__ __align__(16) signed char As[2 * 128 * 64];
    __shared__ __align__(16) signed char Bs[2 * 128 * 64];
    const int nb = D_IN / 128;
    const int m0 = (blockIdx.x / nb) * 128, n0 = (blockIdx.x % nb) * 128;
    v4i acc[4][4];
    v4i zero = {0, 0, 0, 0};
#pragma unroll
    for (int i = 0; i < 4; i++)
#pragma unroll
        for (int j = 0; j < 4; j++) acc[i][j] = zero;
    int8_mainloop(Aq, Bq, D_HID, m0, n0, As, Bs, acc);

    const int tid = threadIdx.x, lane = tid & 63, wave = tid >> 6;
    const int wm = (wave & 1) << 6, wn = (wave >> 1) << 6;
    const int lm = lane & 15, lq = lane >> 4;
    float s2 = scal[7];
    int zx = iscal[1];
#pragma unroll
    for (int j = 0; j < 4; j++) {
        int n = n0 + wn + j * 16 + lm;
        int rsn = rsum[n];
        float bn = bias[n];
#pragma unroll
        for (int i = 0; i < 4; i++) {
            int mb = m0 + wm + i * 16 + lq * 4;
#pragma unroll
            for (int rg = 0; rg < 4; rg++) {
                int v = acc[i][j][rg] - zx * rsn;
                Out[(long)(mb + rg) * D_IN + n] = (float)v * s2 + bn;
            }
        }
    }
}

extern "C" void kernel_launch(void* const* d_in, const int* in_sizes, int n_in,
                              void* d_out, int out_size, void* d_ws, size_t ws_size,
                              hipStream_t stream) {
    const float* x  = (const float*)d_in[0];
    const float* W1 = (const float*)d_in[1];
    const float* b1 = (const float*)d_in[2];
    const float* W2 = (const float*)d_in[3];
    const float* b2 = (const float*)d_in[4];

    char* ws = (char*)d_ws;
    unsigned* slots    = (unsigned*)(ws + OFF_SLOTS);
    float* scal        = (float*)(ws + OFF_SCAL);
    int* iscal         = (int*)(ws + OFF_ISCAL);
    signed char* xq    = (signed char*)(ws + OFF_XQ);
    signed char* w1q   = (signed char*)(ws + OFF_W1Q);
    signed char* w2q   = (signed char*)(ws + OFF_W2Q);
    int* rs1           = (int*)(ws + OFF_RS1);
    int* rs2           = (int*)(ws + OFF_RS2);
    _Float16* h        = (_Float16*)(ws + OFF_H);
    signed char* hq    = (signed char*)(ws + OFF_HQ);

    k_init<<<1, 64, 0, stream>>>(slots);
    k_minmax<<<2048, 256, 0, stream>>>((const float4*)x, M_TOK * D_IN / 4, slots);
    k_absmax<<<512, 256, 0, stream>>>((const float4*)W1, D_HID * D_IN / 4, slots, 2);
    k_absmax<<<512, 256, 0, stream>>>((const float4*)W2, D_IN * D_HID / 4, slots, 3);
    k_scales1<<<1, 1, 0, stream>>>(slots, scal, iscal);
    k_quant_x<<<2048, 256, 0, stream>>>((const float4*)x, (int*)xq, M_TOK * D_IN / 4, scal);
    k_quant_w<<<D_HID, 256, 0, stream>>>(W1, w1q, rs1, D_IN, scal, 2);
    k_quant_w<<<D_IN, 256, 0, stream>>>(W2, w2q, rs2, D_HID, scal, 3);
    k_gemm1<<<(M_TOK / 128) * (D_HID / 128), 256, 0, stream>>>(xq, w1q, h, scal, iscal, rs1, b1, slots);
    k_scales2<<<1, 1, 0, stream>>>(slots, scal, iscal);
    k_quant_h<<<4096, 256, 0, stream>>>((const f16x8*)h, (int2*)hq, M_TOK * D_HID / 8, scal);
    k_gemm2<<<(M_TOK / 128) * (D_IN / 128), 256, 0, stream>>>(hq, w2q, (float*)d_out, scal, iscal, rs2, b2);
}